// Round 12
// baseline (181.735 us; speedup 1.0000x reference)
//
#include <hip/hip_runtime.h>

// Problem constants
#define BATCH 32
#define CIN   256
#define CR    8
#define HDIM  56
#define WDIM  56
#define HW    3136          // 56*56 (even -> pixel pairs never straddle images)
#define COUT  44            // 8 z_norm + 36 interactions

#define TILE  128           // k1: pixels per block (lane owns a pixel pair)

typedef float f32x2 __attribute__((ext_vector_type(2)));

// upper-triangular pair table for the 36 interaction channels
__device__ __constant__ const int PI36[36] =
    {0,0,0,0,0,0,0,0, 1,1,1,1,1,1,1, 2,2,2,2,2,2, 3,3,3,3,3, 4,4,4,4, 5,5,5, 6,6, 7};
__device__ __constant__ const int PJ36[36] =
    {0,1,2,3,4,5,6,7, 1,2,3,4,5,6,7, 2,3,4,5,6,7, 3,4,5,6,7, 4,5,6,7, 5,6,7, 6,7, 7};

// ---------------------------------------------------------------------------
// Kernel 1: 1x1 conv reduce (256->8) + BN + ReLU.
// nt x WIDTH experiment. R9/R11 proved nt loads are worth ~9us at dword
// width (2.7 TB/s). Width was only ever tested with CACHED loads (R6/R7),
// where (a) the dirty-poison eviction tax dominated the fabric and (b) R6's
// LDS layout had a ~32-way write conflict -- both masked any request-rate
// effect. This version: nt float2 (8B/lane, 512B/wave-request, 2x bytes per
// request), R4's proven pipeline/occupancy structure, and a conflict-free
// LDS combine layout.
//   512 thr = 8 waves over a 128-px tile; wave w reduces cin [32w,32w+32)
// with a 2-buffer 8-deep pipeline (8-16 nt loads in flight/wave). Weights
// wave-uniform -> scalar loads. Grid 784 blocks, 4 blocks/CU (32KB LDS,
// <=64 VGPR) = 32 waves/CU.
//   LDS pacc[wv][c][px]: phase-1 writes are f32x2 at 8B lane-stride (~2-way,
// free); epilogue reads 8-way conflicted but run once (~negligible).
// z written channels-last [pixel][8] for kernel 2 (cached store, k2 re-reads).
// ---------------------------------------------------------------------------
__global__ __launch_bounds__(512, 8) void k1_reduce_bn_relu(
    const float* __restrict__ x, const float* __restrict__ wr,
    const float* __restrict__ gamma, const float* __restrict__ beta,
    const float* __restrict__ mean, const float* __restrict__ var,
    float* __restrict__ z)
{
    const int tid  = threadIdx.x;
    const int lane = tid & 63;
    const int wv   = __builtin_amdgcn_readfirstlane(tid >> 6);   // 0..7
    const int px0  = blockIdx.x * TILE;          // block's first pixel
    const int gp   = px0 + 2 * lane;             // lane's pixel pair
    const int b    = gp / HW;                    // pair never straddles images
    const int p    = gp - b * HW;
    const int cin0 = wv * 32;

    const float* __restrict__ xq =
        x + (size_t)b * CIN * HW + (size_t)cin0 * HW + p;

    float a0[CR], a1[CR];
#pragma unroll
    for (int c = 0; c < CR; ++c) { a0[c] = 0.f; a1[c] = 0.f; }

    f32x2 xa[8], xb[8];
    auto loadx = [&](f32x2 (&arr)[8], int base) {
#pragma unroll
        for (int j = 0; j < 8; ++j)
            arr[j] = __builtin_nontemporal_load(
                reinterpret_cast<const f32x2*>(xq + (size_t)(base + j) * HW));
    };
    auto consume = [&](const f32x2 (&arr)[8], int base) {
#pragma unroll
        for (int j = 0; j < 8; ++j) {
            const int cin = cin0 + base + j;              // wave-uniform
#pragma unroll
            for (int c = 0; c < CR; ++c) {
                const float wgt = wr[c * CIN + cin];      // scalar load
                a0[c] = fmaf(arr[j][0], wgt, a0[c]);
                a1[c] = fmaf(arr[j][1], wgt, a1[c]);
            }
        }
    };

    loadx(xa, 0);
    loadx(xb, 8);            // 16 nt loads (8KB/wave) in flight
    consume(xa, 0);
    loadx(xa, 16);           // issued while xb in flight
    consume(xb, 8);
    loadx(xb, 24);
    consume(xa, 16);
    consume(xb, 24);

    // cross-wave combine; [wv][c][px] so phase-1 writes are conflict-free
    __shared__ float pacc[8][CR][TILE];          // 32 KB
#pragma unroll
    for (int c = 0; c < CR; ++c) {
        f32x2 v2; v2[0] = a0[c]; v2[1] = a1[c];
        *reinterpret_cast<f32x2*>(&pacc[wv][c][2 * lane]) = v2;
    }
    __syncthreads();

    // 1024 outputs (128 px * 8 ch), 512 threads -> 2 each; v = px*8 + c so
    // the z store is fully contiguous per block.
#pragma unroll
    for (int v = tid; v < TILE * CR; v += 512) {
        const int px = v >> 3;
        const int c  = v & 7;
        float s = 0.f;
#pragma unroll
        for (int w = 0; w < 8; ++w) s += pacc[w][c][px];
        const float inv = gamma[c] / sqrtf(var[c] + 1e-5f);
        const float sh  = beta[c] - mean[c] * inv;
        z[(size_t)px0 * CR + v] = fmaxf(fmaf(s, inv, sh), 0.f);
    }
}

// ---------------------------------------------------------------------------
// Kernel 2 (FROZEN from R9/R11 -- part of the best measured configuration):
// depthwise 3x3 * scale + L2 norms + 36 pairwise products -> 44 channels.
// 256-thr block = 4 waves over the same 64 pixels; each wave redundantly
// computes conv+norms and writes an 11-channel slice. nt out stores.
// ---------------------------------------------------------------------------
__global__ __launch_bounds__(256) void k2_dw_norm_inter(
    const float* __restrict__ z, const float* __restrict__ wdw,
    const float* __restrict__ scale, float* __restrict__ out)
{
    const int lane = threadIdx.x & 63;
    const int wv   = __builtin_amdgcn_readfirstlane(threadIdx.x >> 6); // 0..3
    const int t = blockIdx.x * 64 + lane;          // global pixel id
    const int b = t / HW;
    const int p = t - b * HW;
    const int h = p / WDIM;
    const int w = p - h * WDIM;

    const float* __restrict__ zimg = z + (size_t)b * HW * CR;

    // issue all 9 tap loads first (static reg indices, one waitcnt)
    float4 n0[9], n1[9];
    float  mk[9];
#pragma unroll
    for (int dy = -1; dy <= 1; ++dy) {
#pragma unroll
        for (int dx = -1; dx <= 1; ++dx) {
            const int k  = (dy + 1) * 3 + (dx + 1);
            const int hh = h + dy, ww = w + dx;
            const bool ok = (hh >= 0) & (hh < HDIM) & (ww >= 0) & (ww < WDIM);
            const int hc = min(max(hh, 0), HDIM - 1);
            const int wc = min(max(ww, 0), WDIM - 1);
            mk[k] = ok ? 1.0f : 0.0f;
            const float* zn = zimg + (size_t)(hc * WDIM + wc) * CR;
            n0[k] = reinterpret_cast<const float4*>(zn)[0];
            n1[k] = reinterpret_cast<const float4*>(zn)[1];
        }
    }

    const float zc[CR] = {n0[4].x, n0[4].y, n0[4].z, n0[4].w,
                          n1[4].x, n1[4].y, n1[4].z, n1[4].w};

    float tw[CR];
#pragma unroll
    for (int c = 0; c < CR; ++c) tw[c] = 0.f;
#pragma unroll
    for (int k = 0; k < 9; ++k) {
        const float nv[CR] = {n0[k].x, n0[k].y, n0[k].z, n0[k].w,
                              n1[k].x, n1[k].y, n1[k].z, n1[k].w};
#pragma unroll
        for (int c = 0; c < CR; ++c)
            tw[c] = fmaf(nv[c] * mk[k], wdw[c * 9 + k], tw[c]);
    }

    float s1 = 0.f, s2 = 0.f;
#pragma unroll
    for (int c = 0; c < CR; ++c) {
        tw[c] *= scale[c];
        s1 = fmaf(zc[c], zc[c], s1);
        s2 = fmaf(tw[c], tw[c], s2);
    }
    const float r1 = 1.0f / fmaxf(sqrtf(s1), 1e-6f);
    const float r2 = 1.0f / fmaxf(sqrtf(s2), 1e-6f);

    float a[CR], tb[CR];
#pragma unroll
    for (int c = 0; c < CR; ++c) { a[c] = zc[c] * r1; tb[c] = tw[c] * r2; }

    // this wave's 11-channel slice of the 44 outputs, nt stores
    float* op = out + (size_t)b * COUT * HW + p;
#pragma unroll
    for (int c = 0; c < COUT; ++c) {
        if ((c / 11) == wv) {
            const float val = (c < CR) ? a[c]
                                       : a[PI36[c - CR]] * tb[PJ36[c - CR]];
            __builtin_nontemporal_store(val, op + (size_t)c * HW);
        }
    }
}

extern "C" void kernel_launch(void* const* d_in, const int* in_sizes, int n_in,
                              void* d_out, int out_size, void* d_ws, size_t ws_size,
                              hipStream_t stream) {
    const float* x     = (const float*)d_in[0];
    const float* wr    = (const float*)d_in[1];
    const float* gamma = (const float*)d_in[2];
    const float* beta  = (const float*)d_in[3];
    const float* mean  = (const float*)d_in[4];
    const float* var   = (const float*)d_in[5];
    const float* wdw   = (const float*)d_in[6];
    const float* scale = (const float*)d_in[7];
    float* out = (float*)d_out;
    float* z   = (float*)d_ws;   // BATCH*HW*CR floats = 3.21 MB, channels-last

    const int npix = BATCH * HW;              // 100352
    k1_reduce_bn_relu<<<npix / TILE, 512, 0, stream>>>(x, wr, gamma, beta, mean, var, z);
    k2_dw_norm_inter<<<npix / 64, 256, 0, stream>>>(z, wdw, scale, out);
}

// Round 13
// 167.102 us; speedup vs baseline: 1.0876x; 1.0876x over previous
//
#include <hip/hip_runtime.h>

// Problem constants
#define BATCH 32
#define CIN   256
#define CR    8
#define HDIM  56
#define WDIM  56
#define HW    3136          // 56*56 = 49*64 (waves never straddle batch rows)
#define COUT  44            // 8 z_norm + 36 interactions

// upper-triangular pair table for the 36 interaction channels
__device__ __constant__ const int PI36[36] =
    {0,0,0,0,0,0,0,0, 1,1,1,1,1,1,1, 2,2,2,2,2,2, 3,3,3,3,3, 4,4,4,4, 5,5,5, 6,6, 7};
__device__ __constant__ const int PJ36[36] =
    {0,1,2,3,4,5,6,7, 1,2,3,4,5,6,7, 2,3,4,5,6,7, 3,4,5,6,7, 4,5,6,7, 5,6,7, 6,7, 7};

// ---------------------------------------------------------------------------
// FINAL CONFIGURATION (byte-exact R9/R11, the A/B/A-verified best:
// 166.4 / 167.9 us vs 172-176 for every plain-load assembly).
//
// Kernel 1: 1x1 conv reduce (256->8) + BN + ReLU.
// 512 thr = 8 waves over 64 px; wave w reduces cin [32w,32w+32) with a
// 2-buffer 8-deep pipeline; 16KB LDS combine; BN+ReLU fused on store.
// x loads NON-TEMPORAL (R9/R10/R11 A/B/A: worth ~9us -- skips L2/L3
// allocation, avoiding part of the dirty-poison writeback tax measured in
// R8's counters: +41MB WRITE per 103MB read with cached loads). x is read
// exactly once; caching it has no value. z keeps cached stores (k2 re-reads).
// Width x cache-policy matrix fully measured (R4/R6/R7/R9/R12): nt-dword is
// the unique optimum; k1 ~38us = 103MB at the platform's effective ~2.7TB/s.
// ---------------------------------------------------------------------------
__global__ __launch_bounds__(512, 8) void k1_reduce_bn_relu(
    const float* __restrict__ x, const float* __restrict__ wr,
    const float* __restrict__ gamma, const float* __restrict__ beta,
    const float* __restrict__ mean, const float* __restrict__ var,
    float* __restrict__ z)
{
    const int tid  = threadIdx.x;
    const int lane = tid & 63;
    const int wv   = __builtin_amdgcn_readfirstlane(tid >> 6);   // 0..7
    const int pix0 = blockIdx.x * 64;
    const int gp   = pix0 + lane;
    const int b    = gp / HW;
    const int p    = gp - b * HW;
    const int cin0 = wv * 32;

    const float* __restrict__ xq =
        x + (size_t)b * CIN * HW + (size_t)cin0 * HW + p;

    float acc[CR];
#pragma unroll
    for (int c = 0; c < CR; ++c) acc[c] = 0.f;

    float xa[8], xb[8];
    auto loadx = [&](float (&arr)[8], int base) {
#pragma unroll
        for (int j = 0; j < 8; ++j)
            arr[j] = __builtin_nontemporal_load(
                         xq + (size_t)(base + j) * HW);   // nt: no L2/L3 alloc
    };
    auto consume = [&](const float (&arr)[8], int base) {
#pragma unroll
        for (int j = 0; j < 8; ++j) {
            const int cin = cin0 + base + j;              // wave-uniform
#pragma unroll
            for (int c = 0; c < CR; ++c)
                acc[c] = fmaf(arr[j], wr[c * CIN + cin], acc[c]);
        }
    };

    loadx(xa, 0);
    loadx(xb, 8);            // 16 loads in flight
    consume(xa, 0);
    loadx(xa, 16);           // issued while xb in flight
    consume(xb, 8);
    loadx(xb, 24);
    consume(xa, 16);
    consume(xb, 24);

    __shared__ float pacc[8][64][CR];            // 16 KB
#pragma unroll
    for (int c = 0; c < CR; c += 4)
        *reinterpret_cast<float4*>(&pacc[wv][lane][c]) =
            make_float4(acc[c], acc[c + 1], acc[c + 2], acc[c + 3]);
    __syncthreads();

    // 512 outputs (64 px * 8 ch), 512 threads -> 1 each; store coalesced.
    const int c  = tid & 7;
    const int px = tid >> 3;
    float s = 0.f;
#pragma unroll
    for (int w = 0; w < 8; ++w) s += pacc[w][px][c];
    const float inv = gamma[c] / sqrtf(var[c] + 1e-5f);
    const float sh  = beta[c] - mean[c] * inv;
    z[(size_t)pix0 * CR + tid] = fmaxf(fmaf(s, inv, sh), 0.f);  // cached (k2 re-reads)
}

// ---------------------------------------------------------------------------
// Kernel 2: depthwise 3x3 * scale + L2 norms + 36 pairwise products -> 44
// channels. 256-thr block = 4 waves over the same 64 pixels; each wave
// redundantly computes conv+norms (tap loads L1/L2-shared) and writes an
// 11-channel slice (compile-time channel indexing). out stores NON-TEMPORAL
// (write-once data; part of the winning R9/R11 configuration).
// Measured ~5.5us/rep via the R5 rep-loop instrumentation.
// ---------------------------------------------------------------------------
__global__ __launch_bounds__(256) void k2_dw_norm_inter(
    const float* __restrict__ z, const float* __restrict__ wdw,
    const float* __restrict__ scale, float* __restrict__ out)
{
    const int lane = threadIdx.x & 63;
    const int wv   = __builtin_amdgcn_readfirstlane(threadIdx.x >> 6); // 0..3
    const int t = blockIdx.x * 64 + lane;          // global pixel id
    const int b = t / HW;
    const int p = t - b * HW;
    const int h = p / WDIM;
    const int w = p - h * WDIM;

    const float* __restrict__ zimg = z + (size_t)b * HW * CR;

    // issue all 9 tap loads first (static reg indices, one waitcnt)
    float4 n0[9], n1[9];
    float  mk[9];
#pragma unroll
    for (int dy = -1; dy <= 1; ++dy) {
#pragma unroll
        for (int dx = -1; dx <= 1; ++dx) {
            const int k  = (dy + 1) * 3 + (dx + 1);
            const int hh = h + dy, ww = w + dx;
            const bool ok = (hh >= 0) & (hh < HDIM) & (ww >= 0) & (ww < WDIM);
            const int hc = min(max(hh, 0), HDIM - 1);
            const int wc = min(max(ww, 0), WDIM - 1);
            mk[k] = ok ? 1.0f : 0.0f;
            const float* zn = zimg + (size_t)(hc * WDIM + wc) * CR;
            n0[k] = reinterpret_cast<const float4*>(zn)[0];
            n1[k] = reinterpret_cast<const float4*>(zn)[1];
        }
    }

    const float zc[CR] = {n0[4].x, n0[4].y, n0[4].z, n0[4].w,
                          n1[4].x, n1[4].y, n1[4].z, n1[4].w};

    float tw[CR];
#pragma unroll
    for (int c = 0; c < CR; ++c) tw[c] = 0.f;
#pragma unroll
    for (int k = 0; k < 9; ++k) {
        const float nv[CR] = {n0[k].x, n0[k].y, n0[k].z, n0[k].w,
                              n1[k].x, n1[k].y, n1[k].z, n1[k].w};
#pragma unroll
        for (int c = 0; c < CR; ++c)
            tw[c] = fmaf(nv[c] * mk[k], wdw[c * 9 + k], tw[c]);
    }

    float s1 = 0.f, s2 = 0.f;
#pragma unroll
    for (int c = 0; c < CR; ++c) {
        tw[c] *= scale[c];
        s1 = fmaf(zc[c], zc[c], s1);
        s2 = fmaf(tw[c], tw[c], s2);
    }
    const float r1 = 1.0f / fmaxf(sqrtf(s1), 1e-6f);
    const float r2 = 1.0f / fmaxf(sqrtf(s2), 1e-6f);

    float a[CR], tb[CR];
#pragma unroll
    for (int c = 0; c < CR; ++c) { a[c] = zc[c] * r1; tb[c] = tw[c] * r2; }

    // this wave's 11-channel slice of the 44 outputs, nt stores
    float* op = out + (size_t)b * COUT * HW + p;
#pragma unroll
    for (int c = 0; c < COUT; ++c) {
        if ((c / 11) == wv) {
            const float val = (c < CR) ? a[c]
                                       : a[PI36[c - CR]] * tb[PJ36[c - CR]];
            __builtin_nontemporal_store(val, op + (size_t)c * HW);
        }
    }
}

extern "C" void kernel_launch(void* const* d_in, const int* in_sizes, int n_in,
                              void* d_out, int out_size, void* d_ws, size_t ws_size,
                              hipStream_t stream) {
    const float* x     = (const float*)d_in[0];
    const float* wr    = (const float*)d_in[1];
    const float* gamma = (const float*)d_in[2];
    const float* beta  = (const float*)d_in[3];
    const float* mean  = (const float*)d_in[4];
    const float* var   = (const float*)d_in[5];
    const float* wdw   = (const float*)d_in[6];
    const float* scale = (const float*)d_in[7];
    float* out = (float*)d_out;
    float* z   = (float*)d_ws;   // BATCH*HW*CR floats = 3.21 MB, channels-last

    const int npix = BATCH * HW;              // 100352
    k1_reduce_bn_relu<<<npix / 64, 512, 0, stream>>>(x, wr, gamma, beta, mean, var, z);
    k2_dw_norm_inter<<<npix / 64, 256, 0, stream>>>(z, wdw, scale, out);
}